// Round 20
// baseline (142.653 us; speedup 1.0000x reference)
//
#include <hip/hip_runtime.h>
#include <math.h>

#define LQ 1024      // sequence length
#define EE 1024      // embed dim
#define NH 16        // heads
#define HD 64        // head dim
#define SCALING 0.125f

typedef unsigned short u16;
typedef __bf16 bf16x8 __attribute__((ext_vector_type(8)));
typedef __bf16 bf16x4 __attribute__((ext_vector_type(4)));
typedef float f32x4 __attribute__((ext_vector_type(4)));

#define MFMA16(a, b, c) __builtin_amdgcn_mfma_f32_16x16x32_bf16(a, b, c, 0, 0, 0)
#define BAR() __builtin_amdgcn_s_barrier()

__device__ __forceinline__ void split_bf16(float x, __bf16& h, __bf16& l)
{
    h = (__bf16)x;
    l = (__bf16)(x - (float)h);
}

__device__ __forceinline__ u16 bf16_bits(__bf16 v)
{
    union { __bf16 b; u16 u; } cv;
    cv.b = v;
    return cv.u;
}

// ---------------------------------------------------------------------------
// Merged conversion kernel, 2048 blocks:
//   blocks 0..1023:  hidden (4096x1024 fp32) -> Ah (4096x1024 bf16, hi only)
//   blocks 1024..2047: W -> BT (1024x1024 bf16, hi only, [n][k])
// ---------------------------------------------------------------------------
__global__ __launch_bounds__(256) void conv_all(
    const float* __restrict__ A,
    const float* __restrict__ Wq, const float* __restrict__ Wk,
    const float* __restrict__ Wv, const float* __restrict__ Wo,
    __bf16* __restrict__ Ah,
    __bf16* __restrict__ BTq, __bf16* __restrict__ BTk,
    __bf16* __restrict__ BTv, __bf16* __restrict__ BTo)
{
    __shared__ float tbuf[64][65];
    const int bid = blockIdx.x;
    const int tid = threadIdx.x;

    if (bid < 1024) {
        int t = bid * 256 + tid;
#pragma unroll
        for (int it = 0; it < 4; it++) {
            int f = t + it * 262144;            // float4 index, total 1048576
            int m = f >> 8, c4 = f & 255;
            float4 x = ((const float4*)A)[f];
            bf16x4 hv;
            hv[0] = (__bf16)x.x; hv[1] = (__bf16)x.y;
            hv[2] = (__bf16)x.z; hv[3] = (__bf16)x.w;
            *(bf16x4*)(Ah + (size_t)m * 1024 + c4 * 4) = hv;
        }
        return;
    }

    const int b2 = bid - 1024;
    const int z  = b2 >> 8;                     // 0..3
    const int rem = b2 & 255;
    const int n0 = (rem & 15) * 64, k0 = (rem >> 4) * 64;
    const float* W = (z == 0) ? Wq : (z == 1) ? Wk : (z == 2) ? Wv : Wo;
    __bf16* BT     = (z == 0) ? BTq : (z == 1) ? BTk : (z == 2) ? BTv : BTo;

#pragma unroll
    for (int rr = 0; rr < 4; rr++) {
        int f = rr * 256 + tid;            // 1024 float4 loads
        int kl = f >> 4, n4 = f & 15;
        float4 x = *(const float4*)&W[(size_t)(k0 + kl) * EE + n0 + n4 * 4];
        tbuf[kl][n4 * 4 + 0] = x.x;
        tbuf[kl][n4 * 4 + 1] = x.y;
        tbuf[kl][n4 * 4 + 2] = x.z;
        tbuf[kl][n4 * 4 + 3] = x.w;
    }
    __syncthreads();
#pragma unroll
    for (int rr = 0; rr < 2; rr++) {
        int f = rr * 256 + tid;            // 512 chunks of 8 along k
        int nl = f >> 3, c8 = f & 7;
        bf16x8 hv;
#pragma unroll
        for (int j = 0; j < 8; j++) hv[j] = (__bf16)tbuf[c8 * 8 + j][nl];
        *(bf16x8*)(BT + (size_t)(n0 + nl) * 1024 + k0 + c8 * 8) = hv;
    }
}

// ---------------------------------------------------------------------------
// Fused QKV projection: 256x256 tile, BK=64, 8 waves, 8-PHASE pipeline
// (R10 schedule), K' = 1024 (pure bf16). Coalesced epilogues (R18).
// ---------------------------------------------------------------------------
__global__ __launch_bounds__(512, 2) void qkv_mfma(
    const u16* __restrict__ Ah, const u16* __restrict__ BTall,
    const float* __restrict__ bq, const float* __restrict__ bk, const float* __restrict__ bv,
    __bf16* __restrict__ qo, __bf16* __restrict__ ko, __bf16* __restrict__ vto)
{
    const int wg   = blockIdx.x;                 // 0..191
    const int xcd  = wg & 7, idx = wg >> 3;      // 24 tiles per XCD
    const int tile = xcd * 24 + idx;
    const int by   = tile / 12, bx = tile % 12;  // by 0..15, bx 0..11

    __shared__ __attribute__((aligned(16))) u16 smem[65536];   // 128 KB
    u16 (*Ab_lds)[2][8192] = (u16(*)[2][8192])smem;            // [2][2][8192]
    u16 (*Bb_lds)[2][8192] = (u16(*)[2][8192])(smem + 32768);

    const int tid  = threadIdx.x;
    const int lane = tid & 63;
    const int wave = tid >> 6;                   // 0..7
    const int wr   = wave >> 2, wc = wave & 3;   // 2M x 4N, wave tile 128x64
    const int rl   = lane & 15, lq = lane >> 4;

    const int m0    = by * 256;
    const int nrow0 = bx * 256;                  // rows into concatenated BT

    f32x4 acc[8][4] = {};
    bf16x8 af[2][4], bn0[2][2], bn1[2][2];

    auto stA = [&](int buf, int half, int kt) {
        int k0 = kt * 64;
#pragma unroll
        for (int it = 0; it < 2; it++) {
            int c = it * 512 + tid, k2 = c >> 7, row = c & 127;
            __builtin_amdgcn_global_load_lds(
                Ah + (size_t)(m0 + half * 128 + row) * 1024 + k0 + k2 * 8,
                &Ab_lds[buf][half][c * 8], 16, 0, 0);
        }
    };
    auto stB = [&](int buf, int half, int kt) {
        int k0 = kt * 64;
#pragma unroll
        for (int it = 0; it < 2; it++) {
            int c = it * 512 + tid, k2 = c >> 7, row = c & 127;
            __builtin_amdgcn_global_load_lds(
                BTall + (size_t)(nrow0 + half * 128 + row) * 1024 + k0 + k2 * 8,
                &Bb_lds[buf][half][c * 8], 16, 0, 0);
        }
    };
    auto rdA = [&](int buf, int mh) {
#pragma unroll
        for (int kk = 0; kk < 2; kk++)
#pragma unroll
            for (int mi = 0; mi < 4; mi++)
                af[kk][mi] = *(const bf16x8*)&Ab_lds[buf][wr]
                    [((kk * 4 + lq) * 128 + mh * 64 + mi * 16 + rl) * 8];
    };
    auto rdB = [&](int buf, int nh, bf16x8 (&bf)[2][2]) {
#pragma unroll
        for (int kk = 0; kk < 2; kk++)
#pragma unroll
            for (int ni = 0; ni < 2; ni++)
                bf[kk][ni] = *(const bf16x8*)&Bb_lds[buf][wc >> 1]
                    [((kk * 4 + lq) * 128 + (wc & 1) * 64 + nh * 32 + ni * 16 + rl) * 8];
    };
    auto mfma_q = [&](int mh, int nh, bf16x8 (&bf)[2][2]) {
        __builtin_amdgcn_s_setprio(1);
#pragma unroll
        for (int kk = 0; kk < 2; kk++)
#pragma unroll
            for (int mi = 0; mi < 4; mi++)
#pragma unroll
                for (int ni = 0; ni < 2; ni++)
                    acc[mh * 4 + mi][nh * 2 + ni] =
                        MFMA16(af[kk][mi], bf[kk][ni], acc[mh * 4 + mi][nh * 2 + ni]);
        __builtin_amdgcn_s_setprio(0);
    };

    auto body = [&](int t, bool last) {
        rdA(0, 0); rdB(0, 0, bn0);
        stA(1, 0, t + 1);
        BAR(); mfma_q(0, 0, bn0); BAR();
        rdB(0, 1, bn1);
        stA(1, 1, t + 1);
        BAR(); mfma_q(0, 1, bn1); BAR();
        rdA(0, 1);
        if (!last) stB(0, 0, t + 2);
        BAR(); mfma_q(1, 0, bn0); BAR();
        if (!last) {
            stB(0, 1, t + 2);
            asm volatile("s_waitcnt vmcnt(4)" ::: "memory");
        } else {
            asm volatile("s_waitcnt vmcnt(0)" ::: "memory");
        }
        BAR(); mfma_q(1, 1, bn1); BAR();
        rdA(1, 0); rdB(1, 0, bn0);
        if (!last) stA(0, 0, t + 2);
        BAR(); mfma_q(0, 0, bn0); BAR();
        rdB(1, 1, bn1);
        if (!last) stA(0, 1, t + 2);
        BAR(); mfma_q(0, 1, bn1); BAR();
        rdA(1, 1);
        if (!last) stB(1, 0, t + 3);
        BAR(); mfma_q(1, 0, bn0); BAR();
        if (!last) {
            stB(1, 1, t + 3);
            asm volatile("s_waitcnt vmcnt(4)" ::: "memory");
        }
        BAR(); mfma_q(1, 1, bn1); BAR();
    };

    stB(0, 0, 0); stB(0, 1, 0);
    stA(0, 0, 0); stA(0, 1, 0);
    stB(1, 0, 1); stB(1, 1, 1);
    asm volatile("s_waitcnt vmcnt(4)" ::: "memory");
    BAR();

    for (int i = 0; i < 7; i++) body(2 * i, false);   // K' = 1024 -> 16 tiles
    body(14, true);

    // ---- epilogue ----
    const int z   = bx >> 2;                     // 0:q 1:k 2:v (uniform)
    const int n0l = (bx & 3) * 256;
    const float* bias = (z == 0) ? bq : (z == 1) ? bk : bv;
    const float qs    = (z == 0) ? SCALING : 1.0f;
    const int b  = m0 >> 10;
    const int t0 = m0 & 1023;

    if (z < 2) {
        __bf16* O = (z == 0) ? qo : ko;
#pragma unroll
        for (int mi = 0; mi < 8; mi++)
#pragma unroll
            for (int ni = 0; ni < 4; ni++) {
                int col = wc * 64 + ni * 16 + rl;
                float bb = bias[n0l + col];
                int c = col >> 3, j = col & 7;
#pragma unroll
                for (int r = 0; r < 4; r++) {
                    int row = wr * 128 + mi * 16 + lq * 4 + r;
                    smem[((row << 5) + (c ^ (row & 15))) * 8 + j] =
                        bf16_bits((__bf16)((acc[mi][ni][r] + bb) * qs));
                }
            }
        __syncthreads();
        const int h0 = n0l >> 6;
#pragma unroll
        for (int it = 0; it < 16; it++) {
            int id = it * 512 + tid;             // 8192 16B-chunks
            int row = id >> 5, c = id & 31;
            bf16x8 vv = *(const bf16x8*)&smem[((row << 5) + (c ^ (row & 15))) * 8];
            __bf16* dst = O + ((size_t)((b * NH + h0 + (c >> 3)) * LQ) + t0 + row) * HD
                            + (c & 7) * 8;
            *(bf16x8*)dst = vv;
        }
    } else {
        // v: write vtb[bh][d][t] directly, packed 8B stores
#pragma unroll
        for (int mi = 0; mi < 8; mi++)
#pragma unroll
            for (int ni = 0; ni < 4; ni++) {
                int n = n0l + wc * 64 + ni * 16 + rl;
                int h = n >> 6, d = n & 63;
                float bb = bias[n];
                bf16x4 pv;
#pragma unroll
                for (int r = 0; r < 4; r++) pv[r] = (__bf16)(acc[mi][ni][r] + bb);
                int t = t0 + wr * 128 + mi * 16 + lq * 4;
                *(bf16x4*)(vto + ((size_t)(b * NH + h) * HD + d) * LQ + t) = pv;
            }
    }
}

// ---------------------------------------------------------------------------
// Output projection: 128x128 tile, BK=64, 8 waves, counted-vmcnt pipeline,
// K' = 1024 (pure bf16). Grid 256. Ao stride 1024 (hi only).
// ---------------------------------------------------------------------------
__device__ __forceinline__ void stage_op(
    const u16* __restrict__ Ab, const u16* __restrict__ Bb,
    int m0, int nrow0, int k0, int tid, u16* As, u16* Bs)
{
#pragma unroll
    for (int it = 0; it < 2; it++) {
        int c = it * 512 + tid;
        int k2 = c >> 7, row = c & 127;
        __builtin_amdgcn_global_load_lds(Ab + (size_t)(m0 + row) * 1024 + k0 + k2 * 8,
                                         As + (size_t)c * 8, 16, 0, 0);
    }
#pragma unroll
    for (int it = 0; it < 2; it++) {
        int c = it * 512 + tid;
        int k2 = c >> 7, row = c & 127;
        __builtin_amdgcn_global_load_lds(Bb + (size_t)(nrow0 + row) * 1024 + k0 + k2 * 8,
                                         Bs + (size_t)c * 8, 16, 0, 0);
    }
}

__global__ __launch_bounds__(512) void oproj_mfma(
    const u16* __restrict__ Ao, const u16* __restrict__ BTo,
    const float* __restrict__ bo, float* __restrict__ O)
{
    const int wg  = blockIdx.x;
    const int xcd = wg & 7, idx = wg >> 3;
    const int swz = xcd * 32 + idx;
    const int by  = swz >> 3, bx = swz & 7;

    __shared__ __attribute__((aligned(16))) u16 As[2][8192], Bs[2][8192];

    const int tid  = threadIdx.x;
    const int lane = tid & 63;
    const int wave = tid >> 6;
    const int wr   = wave >> 2, wc = wave & 3;
    const int rl   = lane & 15, lq = lane >> 4;

    const int m0 = by * 128, n0 = bx * 128;

    f32x4 acc[4][2] = {};

    auto compute = [&](const u16* Ac, const u16* Bc) {
#pragma unroll
        for (int kk = 0; kk < 2; kk++) {
            bf16x8 af[4], bfr[2];
#pragma unroll
            for (int mi = 0; mi < 4; mi++)
                af[mi] = *(const bf16x8*)(Ac +
                    (size_t)((kk * 4 + lq) * 128 + wr * 64 + mi * 16 + rl) * 8);
#pragma unroll
            for (int ni = 0; ni < 2; ni++)
                bfr[ni] = *(const bf16x8*)(Bc +
                    (size_t)((kk * 4 + lq) * 128 + wc * 32 + ni * 16 + rl) * 8);
#pragma unroll
            for (int mi = 0; mi < 4; mi++)
#pragma unroll
                for (int ni = 0; ni < 2; ni++)
                    acc[mi][ni] = MFMA16(af[mi], bfr[ni], acc[mi][ni]);
        }
    };

    stage_op(Ao, BTo, m0, n0, 0,  tid, As[0], Bs[0]);
    stage_op(Ao, BTo, m0, n0, 64, tid, As[1], Bs[1]);

    int cur = 0;
    for (int i = 0; i < 15; i++) {               // K' = 1024 -> 16 K-tiles
        asm volatile("s_waitcnt vmcnt(4)" ::: "memory");
        __builtin_amdgcn_s_barrier();
        compute(As[cur], Bs[cur]);
        asm volatile("s_waitcnt lgkmcnt(0)" ::: "memory");
        __builtin_amdgcn_s_barrier();
        if (i + 2 < 16)
            stage_op(Ao, BTo, m0, n0, (i + 2) * 64, tid, As[cur], Bs[cur]);
        cur ^= 1;
    }
    asm volatile("s_waitcnt vmcnt(0)" ::: "memory");
    __builtin_amdgcn_s_barrier();
    compute(As[cur], Bs[cur]);

#pragma unroll
    for (int mi = 0; mi < 4; mi++)
#pragma unroll
        for (int ni = 0; ni < 2; ni++) {
            int n = n0 + wc * 32 + ni * 16 + rl;
            float bb = bo[n];
#pragma unroll
            for (int r = 0; r < 4; r++) {
                int m = m0 + wr * 64 + mi * 16 + lq * 4 + r;
                O[(size_t)m * EE + n] = acc[mi][ni][r] + bb;
            }
        }
}

// ---------------------------------------------------------------------------
// MFMA flash attention (fixed-max softmax, QBLK=128, 8 waves).
// R20: (1) bh->XCD affinity: 1-D grid 512, xcd = wg&7, bh = xcd + 8*(inner&7)
// -> each XCD's 8 bh's K/V (2 MB) stay resident in its private L2 (one HBM
// fetch). (2) KVBLK=128 as two 64-tiles per barrier pair: stage 4 tiles,
// 1 barrier, compute both halves, 1 barrier -> 16 barriers total (was 32).
// Numerics bit-identical to R19 (same FP order).
// ---------------------------------------------------------------------------
__device__ __forceinline__ bf16x8 ld_frag(const u16* base, int row, int col)
{
    int off = (row * 128 + col * 2) ^ ((row & 7) << 4);
    return *(const bf16x8*)((const char*)base + off);
}

__global__ __launch_bounds__(512) void attn_mfma(
    const u16* __restrict__ qb, const u16* __restrict__ kb,
    const u16* __restrict__ vtb,
    const float* __restrict__ relk, const float* __restrict__ relv,
    __bf16* __restrict__ Ao)
{
    __shared__ __attribute__((aligned(16))) u16 pool[16384];   // 32 KB: q(16) + p(16)
    __shared__ __attribute__((aligned(16))) u16 k_lds[2][4096];
    __shared__ __attribute__((aligned(16))) u16 v_lds[2][4096];
    __shared__ float R_lds[128 * 9];
    __shared__ float rk_lds[9 * 64];
    __shared__ float rv_lds[9 * 64];

    u16* q_lds = pool;            // 8192 u16

    const int tid   = threadIdx.x;
    const int lane  = tid & 63;
    const int wave  = tid >> 6;                  // 0..7
    const int rl    = lane & 15, lq = lane >> 4;
    const int wg    = blockIdx.x;                // 0..511
    const int xcd   = wg & 7, inner = wg >> 3;   // XCD affinity
    const int bh    = xcd + 8 * (inner & 7);     // bh & 7 == xcd
    const int q0    = (inner >> 3) * 128;        // 0..7 q-blocks

    auto stage64 = [&](u16* kl, u16* vl, int s0) {
        int row = tid >> 3, c8 = tid & 7;
        const u16* srck = kb + ((size_t)bh * LQ + s0 + row) * HD + ((c8 ^ (row & 7)) * 8);
        __builtin_amdgcn_global_load_lds(srck, kl + (size_t)(tid & ~63) * 8, 16, 0, 0);
        const u16* srcv = vtb + ((size_t)bh * HD + row) * LQ + s0 + ((c8 ^ (row & 7)) * 8);
        __builtin_amdgcn_global_load_lds(srcv, vl + (size_t)(tid & ~63) * 8, 16, 0, 0);
    };

    // ---- stage Q block (128x64 bf16) with inverse-swizzled source ----
#pragma unroll
    for (int rr = 0; rr < 2; rr++) {
        int f = rr * 512 + tid;
        int row = f >> 3, c8 = f & 7;
        const u16* src = qb + ((size_t)bh * LQ + q0 + row) * HD + ((c8 ^ (row & 7)) * 8);
        __builtin_amdgcn_global_load_lds(src, q_lds + (size_t)(f & ~63) * 8, 16, 0, 0);
    }
    for (int u = tid; u < 144; u += 512)
        *(float4*)&rk_lds[u * 4] = *(const float4*)&relk[u * 4];
    for (int u = tid; u < 144; u += 512)
        *(float4*)&rv_lds[u * 4] = *(const float4*)&relv[u * 4];
    __syncthreads();

    // ---- R[t][i] = q[t] . relk[i]  (128 x 9) ----
    for (int j = tid; j < 1152; j += 512) {
        int tl = j / 9, i = j - tl * 9;
        float acc = 0.f;
        for (int d = 0; d < 64; d++) {
            int off = (tl * 128 + d * 2) ^ ((tl & 7) << 4);
            float qv = (float)*(const __bf16*)((const char*)q_lds + off);
            acc += qv * rk_lds[i * 64 + d];
        }
        R_lds[tl * 9 + i] = acc;
    }

    bf16x8 qa[2];
    qa[0] = ld_frag(q_lds, wave * 16 + rl, lq * 8);
    qa[1] = ld_frag(q_lds, wave * 16 + rl, 32 + lq * 8);

    __syncthreads();

    f32x4 of[4] = {};
    float l_r[4] = {0.f, 0.f, 0.f, 0.f};

    const u16* pw = pool + 8192 + wave * 1024;
    u16* pww      = pool + 8192 + wave * 1024;

    auto half_body = [&](const u16* kl, const u16* vl, int s0h) {
        // ---- S = Q @ K^T ----
        f32x4 sf[4] = {};
#pragma unroll
        for (int sub = 0; sub < 4; sub++) {
#pragma unroll
            for (int kk = 0; kk < 2; kk++) {
                bf16x8 kf = ld_frag(kl, sub * 16 + rl, kk * 32 + lq * 8);
                sf[sub] = MFMA16(qa[kk], kf, sf[sub]);
            }
        }

        int drel = s0h - q0;
        bool diag = (drel >= -64) && (drel <= 128);
        if (diag) {
#pragma unroll
            for (int sub = 0; sub < 4; sub++) {
#pragma unroll
                for (int r = 0; r < 4; r++) {
                    int tl = wave * 16 + lq * 4 + r;
                    int s  = s0h + sub * 16 + rl;
                    int i  = s - (q0 + tl) + 4;
                    if ((unsigned)i <= 8u) sf[sub][r] += R_lds[tl * 9 + i];
                }
            }
        }

        // ---- P = exp(S), accumulate l, store bf16 ----
#pragma unroll
        for (int sub = 0; sub < 4; sub++) {
#pragma unroll
            for (int r = 0; r < 4; r++) {
                float p = __expf(sf[sub][r]);
                l_r[r] += p;
                int q = lq * 4 + r;
                int off = (q * 128 + (sub * 16 + rl) * 2) ^ ((q & 7) << 4);
                *(__bf16*)((char*)pww + off) = (__bf16)p;
            }
        }

        // ---- O += P @ V ----
#pragma unroll
        for (int kk = 0; kk < 2; kk++) {
            bf16x8 pa = ld_frag(pw, rl, kk * 32 + lq * 8);
#pragma unroll
            for (int dsub = 0; dsub < 4; dsub++) {
                bf16x8 vf = ld_frag(vl, dsub * 16 + rl, kk * 32 + lq * 8);
                of[dsub] = MFMA16(pa, vf, of[dsub]);
            }
        }

        // ---- windowed rel-v term ----
        if (diag) {
#pragma unroll
            for (int r = 0; r < 4; r++) {
                int q  = lq * 4 + r;
                int tl = wave * 16 + q;
#pragma unroll
                for (int i = 0; i < 9; i++) {
                    int s  = q0 + tl + i - 4;
                    int sl = s - s0h;
                    if ((unsigned)sl < 64u) {
                        int off = (q * 128 + sl * 2) ^ ((q & 7) << 4);
                        float p = (float)*(const __bf16*)((const char*)pww + off);
#pragma unroll
                        for (int dsub = 0; dsub < 4; dsub++)
                            of[dsub][r] += p * rv_lds[i * 64 + dsub * 16 + rl];
                    }
                }
            }
        }
    };

    for (int c = 0; c < 8; c++) {
        const int s0 = c * 128;
        stage64(k_lds[0], v_lds[0], s0);
        stage64(k_lds[1], v_lds[1], s0 + 64);
        __syncthreads();                 // all 4 tiles ready (drains vmcnt)
        half_body(k_lds[0], v_lds[0], s0);
        half_body(k_lds[1], v_lds[1], s0 + 64);
        __syncthreads();                 // all waves done reading
    }

    // ---- final normalize ----
#pragma unroll
    for (int r = 0; r < 4; r++) {
        float s = l_r[r];
#pragma unroll
        for (int msk = 8; msk >= 1; msk >>= 1) s += __shfl_xor(s, msk, 64);
        l_r[r] = 1.0f / s;
    }

    // ---- stage hi tile (128 x 64) into pool, then coalesced write ----
#pragma unroll
    for (int dsub = 0; dsub < 4; dsub++) {
#pragma unroll
        for (int r = 0; r < 4; r++) {
            int row = wave * 16 + lq * 4 + r;       // 0..127
            float v = of[dsub][r] * l_r[r];
            int col = dsub * 16 + rl;               // 0..63
            int c = col >> 3, j = col & 7;
            pool[(row * 8 + (c ^ (row & 7))) * 8 + j] = bf16_bits((__bf16)v);
        }
    }
    __syncthreads();
    const int b = bh >> 4, h = bh & 15;
#pragma unroll
    for (int it = 0; it < 2; it++) {
        int id = it * 512 + tid;                    // 1024 16B-chunks
        int row = id >> 3, c = id & 7;
        bf16x8 vv = *(const bf16x8*)&pool[(row * 8 + (c ^ (row & 7))) * 8];
        __bf16* dst = Ao + ((size_t)(b * LQ) + q0 + row) * 1024 + h * 64 + c * 8;
        *(bf16x8*)dst = vv;
    }
}

// ---------------------------------------------------------------------------
extern "C" void kernel_launch(void* const* d_in, const int* in_sizes, int n_in,
                              void* d_out, int out_size, void* d_ws, size_t ws_size,
                              hipStream_t stream)
{
    const float* hidden = (const float*)d_in[0];
    const float* Wq = (const float*)d_in[1];
    const float* bq = (const float*)d_in[2];
    const float* Wk = (const float*)d_in[3];
    const float* bk = (const float*)d_in[4];
    const float* Wv = (const float*)d_in[5];
    const float* bv = (const float*)d_in[6];
    const float* Wo = (const float*)d_in[7];
    const float* bo = (const float*)d_in[8];
    const float* relk = (const float*)d_in[9];
    const float* relv = (const float*)d_in[10];

    char* w = (char*)d_ws;
    // Workspace: Ah/Ao 8 MB at 0 (hi only, stride 1024); BTq 8M (2MB),
    // BTk 10M, BTv 12M (contiguous 3072 rows), BTo 14M; qbw 16M (8MB),
    // kbw 24M (8MB), vtbw 32M (8MB). 40 MB total.
    __bf16* Ah   = (__bf16*)(w);
    __bf16* Ao   = (__bf16*)(w);
    __bf16* BTq  = (__bf16*)(w + (8u << 20));
    __bf16* BTk  = (__bf16*)(w + (10u << 20));
    __bf16* BTv  = (__bf16*)(w + (12u << 20));
    __bf16* BTo  = (__bf16*)(w + (14u << 20));
    __bf16* qbw  = (__bf16*)(w + (16u << 20));
    __bf16* kbw  = (__bf16*)(w + (24u << 20));
    __bf16* vtbw = (__bf16*)(w + (32u << 20));
    float*  out  = (float*)d_out;

    conv_all<<<2048, 256, 0, stream>>>(hidden, Wq, Wk, Wv, Wo, Ah,
                                       BTq, BTk, BTv, BTo);
    qkv_mfma<<<192, 512, 0, stream>>>((const u16*)Ah, (const u16*)BTq,
                                      bq, bk, bv, qbw, kbw, vtbw);
    attn_mfma<<<512, 512, 0, stream>>>((const u16*)qbw, (const u16*)kbw,
        (const u16*)vtbw, relk, relv, Ao);
    oproj_mfma<<<256, 512, 0, stream>>>((const u16*)Ao, (const u16*)BTo, bo, out);
}

// Round 21
// 131.137 us; speedup vs baseline: 1.0878x; 1.0878x over previous
//
#include <hip/hip_runtime.h>
#include <math.h>

#define LQ 1024      // sequence length
#define EE 1024      // embed dim
#define NH 16        // heads
#define HD 64        // head dim
#define SCALING 0.125f

typedef unsigned short u16;
typedef __bf16 bf16x8 __attribute__((ext_vector_type(8)));
typedef __bf16 bf16x4 __attribute__((ext_vector_type(4)));
typedef float f32x4 __attribute__((ext_vector_type(4)));

#define MFMA16(a, b, c) __builtin_amdgcn_mfma_f32_16x16x32_bf16(a, b, c, 0, 0, 0)
#define BAR() __builtin_amdgcn_s_barrier()

__device__ __forceinline__ void split_bf16(float x, __bf16& h, __bf16& l)
{
    h = (__bf16)x;
    l = (__bf16)(x - (float)h);
}

__device__ __forceinline__ u16 bf16_bits(__bf16 v)
{
    union { __bf16 b; u16 u; } cv;
    cv.b = v;
    return cv.u;
}

// ---------------------------------------------------------------------------
// Merged conversion kernel, 2048 blocks:
//   blocks 0..1023:  hidden (4096x1024 fp32) -> Ah (4096x1024 bf16, hi only)
//   blocks 1024..2047: W -> BT (1024x1024 bf16, hi only, [n][k])
// ---------------------------------------------------------------------------
__global__ __launch_bounds__(256) void conv_all(
    const float* __restrict__ A,
    const float* __restrict__ Wq, const float* __restrict__ Wk,
    const float* __restrict__ Wv, const float* __restrict__ Wo,
    __bf16* __restrict__ Ah,
    __bf16* __restrict__ BTq, __bf16* __restrict__ BTk,
    __bf16* __restrict__ BTv, __bf16* __restrict__ BTo)
{
    __shared__ float tbuf[64][65];
    const int bid = blockIdx.x;
    const int tid = threadIdx.x;

    if (bid < 1024) {
        int t = bid * 256 + tid;
#pragma unroll
        for (int it = 0; it < 4; it++) {
            int f = t + it * 262144;            // float4 index, total 1048576
            int m = f >> 8, c4 = f & 255;
            float4 x = ((const float4*)A)[f];
            bf16x4 hv;
            hv[0] = (__bf16)x.x; hv[1] = (__bf16)x.y;
            hv[2] = (__bf16)x.z; hv[3] = (__bf16)x.w;
            *(bf16x4*)(Ah + (size_t)m * 1024 + c4 * 4) = hv;
        }
        return;
    }

    const int b2 = bid - 1024;
    const int z  = b2 >> 8;                     // 0..3
    const int rem = b2 & 255;
    const int n0 = (rem & 15) * 64, k0 = (rem >> 4) * 64;
    const float* W = (z == 0) ? Wq : (z == 1) ? Wk : (z == 2) ? Wv : Wo;
    __bf16* BT     = (z == 0) ? BTq : (z == 1) ? BTk : (z == 2) ? BTv : BTo;

#pragma unroll
    for (int rr = 0; rr < 4; rr++) {
        int f = rr * 256 + tid;            // 1024 float4 loads
        int kl = f >> 4, n4 = f & 15;
        float4 x = *(const float4*)&W[(size_t)(k0 + kl) * EE + n0 + n4 * 4];
        tbuf[kl][n4 * 4 + 0] = x.x;
        tbuf[kl][n4 * 4 + 1] = x.y;
        tbuf[kl][n4 * 4 + 2] = x.z;
        tbuf[kl][n4 * 4 + 3] = x.w;
    }
    __syncthreads();
#pragma unroll
    for (int rr = 0; rr < 2; rr++) {
        int f = rr * 256 + tid;            // 512 chunks of 8 along k
        int nl = f >> 3, c8 = f & 7;
        bf16x8 hv;
#pragma unroll
        for (int j = 0; j < 8; j++) hv[j] = (__bf16)tbuf[c8 * 8 + j][nl];
        *(bf16x8*)(BT + (size_t)(n0 + nl) * 1024 + k0 + c8 * 8) = hv;
    }
}

// ---------------------------------------------------------------------------
// Fused QKV projection: 256x256 tile, BK=64, 8 waves, 8-PHASE pipeline
// (R10 schedule), K' = 1024 (pure bf16). Coalesced epilogues (R18).
// ---------------------------------------------------------------------------
__global__ __launch_bounds__(512, 2) void qkv_mfma(
    const u16* __restrict__ Ah, const u16* __restrict__ BTall,
    const float* __restrict__ bq, const float* __restrict__ bk, const float* __restrict__ bv,
    __bf16* __restrict__ qo, __bf16* __restrict__ ko, __bf16* __restrict__ vto)
{
    const int wg   = blockIdx.x;                 // 0..191
    const int xcd  = wg & 7, idx = wg >> 3;      // 24 tiles per XCD
    const int tile = xcd * 24 + idx;
    const int by   = tile / 12, bx = tile % 12;  // by 0..15, bx 0..11

    __shared__ __attribute__((aligned(16))) u16 smem[65536];   // 128 KB
    u16 (*Ab_lds)[2][8192] = (u16(*)[2][8192])smem;            // [2][2][8192]
    u16 (*Bb_lds)[2][8192] = (u16(*)[2][8192])(smem + 32768);

    const int tid  = threadIdx.x;
    const int lane = tid & 63;
    const int wave = tid >> 6;                   // 0..7
    const int wr   = wave >> 2, wc = wave & 3;   // 2M x 4N, wave tile 128x64
    const int rl   = lane & 15, lq = lane >> 4;

    const int m0    = by * 256;
    const int nrow0 = bx * 256;                  // rows into concatenated BT

    f32x4 acc[8][4] = {};
    bf16x8 af[2][4], bn0[2][2], bn1[2][2];

    auto stA = [&](int buf, int half, int kt) {
        int k0 = kt * 64;
#pragma unroll
        for (int it = 0; it < 2; it++) {
            int c = it * 512 + tid, k2 = c >> 7, row = c & 127;
            __builtin_amdgcn_global_load_lds(
                Ah + (size_t)(m0 + half * 128 + row) * 1024 + k0 + k2 * 8,
                &Ab_lds[buf][half][c * 8], 16, 0, 0);
        }
    };
    auto stB = [&](int buf, int half, int kt) {
        int k0 = kt * 64;
#pragma unroll
        for (int it = 0; it < 2; it++) {
            int c = it * 512 + tid, k2 = c >> 7, row = c & 127;
            __builtin_amdgcn_global_load_lds(
                BTall + (size_t)(nrow0 + half * 128 + row) * 1024 + k0 + k2 * 8,
                &Bb_lds[buf][half][c * 8], 16, 0, 0);
        }
    };
    auto rdA = [&](int buf, int mh) {
#pragma unroll
        for (int kk = 0; kk < 2; kk++)
#pragma unroll
            for (int mi = 0; mi < 4; mi++)
                af[kk][mi] = *(const bf16x8*)&Ab_lds[buf][wr]
                    [((kk * 4 + lq) * 128 + mh * 64 + mi * 16 + rl) * 8];
    };
    auto rdB = [&](int buf, int nh, bf16x8 (&bf)[2][2]) {
#pragma unroll
        for (int kk = 0; kk < 2; kk++)
#pragma unroll
            for (int ni = 0; ni < 2; ni++)
                bf[kk][ni] = *(const bf16x8*)&Bb_lds[buf][wc >> 1]
                    [((kk * 4 + lq) * 128 + (wc & 1) * 64 + nh * 32 + ni * 16 + rl) * 8];
    };
    auto mfma_q = [&](int mh, int nh, bf16x8 (&bf)[2][2]) {
        __builtin_amdgcn_s_setprio(1);
#pragma unroll
        for (int kk = 0; kk < 2; kk++)
#pragma unroll
            for (int mi = 0; mi < 4; mi++)
#pragma unroll
                for (int ni = 0; ni < 2; ni++)
                    acc[mh * 4 + mi][nh * 2 + ni] =
                        MFMA16(af[kk][mi], bf[kk][ni], acc[mh * 4 + mi][nh * 2 + ni]);
        __builtin_amdgcn_s_setprio(0);
    };

    auto body = [&](int t, bool last) {
        rdA(0, 0); rdB(0, 0, bn0);
        stA(1, 0, t + 1);
        BAR(); mfma_q(0, 0, bn0); BAR();
        rdB(0, 1, bn1);
        stA(1, 1, t + 1);
        BAR(); mfma_q(0, 1, bn1); BAR();
        rdA(0, 1);
        if (!last) stB(0, 0, t + 2);
        BAR(); mfma_q(1, 0, bn0); BAR();
        if (!last) {
            stB(0, 1, t + 2);
            asm volatile("s_waitcnt vmcnt(4)" ::: "memory");
        } else {
            asm volatile("s_waitcnt vmcnt(0)" ::: "memory");
        }
        BAR(); mfma_q(1, 1, bn1); BAR();
        rdA(1, 0); rdB(1, 0, bn0);
        if (!last) stA(0, 0, t + 2);
        BAR(); mfma_q(0, 0, bn0); BAR();
        rdB(1, 1, bn1);
        if (!last) stA(0, 1, t + 2);
        BAR(); mfma_q(0, 1, bn1); BAR();
        rdA(1, 1);
        if (!last) stB(1, 0, t + 3);
        BAR(); mfma_q(1, 0, bn0); BAR();
        if (!last) {
            stB(1, 1, t + 3);
            asm volatile("s_waitcnt vmcnt(4)" ::: "memory");
        }
        BAR(); mfma_q(1, 1, bn1); BAR();
    };

    stB(0, 0, 0); stB(0, 1, 0);
    stA(0, 0, 0); stA(0, 1, 0);
    stB(1, 0, 1); stB(1, 1, 1);
    asm volatile("s_waitcnt vmcnt(4)" ::: "memory");
    BAR();

    for (int i = 0; i < 7; i++) body(2 * i, false);   // K' = 1024 -> 16 tiles
    body(14, true);

    // ---- epilogue ----
    const int z   = bx >> 2;                     // 0:q 1:k 2:v (uniform)
    const int n0l = (bx & 3) * 256;
    const float* bias = (z == 0) ? bq : (z == 1) ? bk : bv;
    const float qs    = (z == 0) ? SCALING : 1.0f;
    const int b  = m0 >> 10;
    const int t0 = m0 & 1023;

    if (z < 2) {
        __bf16* O = (z == 0) ? qo : ko;
#pragma unroll
        for (int mi = 0; mi < 8; mi++)
#pragma unroll
            for (int ni = 0; ni < 4; ni++) {
                int col = wc * 64 + ni * 16 + rl;
                float bb = bias[n0l + col];
                int c = col >> 3, j = col & 7;
#pragma unroll
                for (int r = 0; r < 4; r++) {
                    int row = wr * 128 + mi * 16 + lq * 4 + r;
                    smem[((row << 5) + (c ^ (row & 15))) * 8 + j] =
                        bf16_bits((__bf16)((acc[mi][ni][r] + bb) * qs));
                }
            }
        __syncthreads();
        const int h0 = n0l >> 6;
#pragma unroll
        for (int it = 0; it < 16; it++) {
            int id = it * 512 + tid;             // 8192 16B-chunks
            int row = id >> 5, c = id & 31;
            bf16x8 vv = *(const bf16x8*)&smem[((row << 5) + (c ^ (row & 15))) * 8];
            __bf16* dst = O + ((size_t)((b * NH + h0 + (c >> 3)) * LQ) + t0 + row) * HD
                            + (c & 7) * 8;
            *(bf16x8*)dst = vv;
        }
    } else {
        // v: write vtb[bh][d][t] directly, packed 8B stores
#pragma unroll
        for (int mi = 0; mi < 8; mi++)
#pragma unroll
            for (int ni = 0; ni < 4; ni++) {
                int n = n0l + wc * 64 + ni * 16 + rl;
                int h = n >> 6, d = n & 63;
                float bb = bias[n];
                bf16x4 pv;
#pragma unroll
                for (int r = 0; r < 4; r++) pv[r] = (__bf16)(acc[mi][ni][r] + bb);
                int t = t0 + wr * 128 + mi * 16 + lq * 4;
                *(bf16x4*)(vto + ((size_t)(b * NH + h) * HD + d) * LQ + t) = pv;
            }
    }
}

// ---------------------------------------------------------------------------
// Output projection: 128x128 tile, BK=64, 8 waves, counted-vmcnt pipeline,
// K' = 1024 (pure bf16). Grid 256. Ao stride 1024 (hi only).
// ---------------------------------------------------------------------------
__device__ __forceinline__ void stage_op(
    const u16* __restrict__ Ab, const u16* __restrict__ Bb,
    int m0, int nrow0, int k0, int tid, u16* As, u16* Bs)
{
#pragma unroll
    for (int it = 0; it < 2; it++) {
        int c = it * 512 + tid;
        int k2 = c >> 7, row = c & 127;
        __builtin_amdgcn_global_load_lds(Ab + (size_t)(m0 + row) * 1024 + k0 + k2 * 8,
                                         As + (size_t)c * 8, 16, 0, 0);
    }
#pragma unroll
    for (int it = 0; it < 2; it++) {
        int c = it * 512 + tid;
        int k2 = c >> 7, row = c & 127;
        __builtin_amdgcn_global_load_lds(Bb + (size_t)(nrow0 + row) * 1024 + k0 + k2 * 8,
                                         Bs + (size_t)c * 8, 16, 0, 0);
    }
}

__global__ __launch_bounds__(512) void oproj_mfma(
    const u16* __restrict__ Ao, const u16* __restrict__ BTo,
    const float* __restrict__ bo, float* __restrict__ O)
{
    const int wg  = blockIdx.x;
    const int xcd = wg & 7, idx = wg >> 3;
    const int swz = xcd * 32 + idx;
    const int by  = swz >> 3, bx = swz & 7;

    __shared__ __attribute__((aligned(16))) u16 As[2][8192], Bs[2][8192];

    const int tid  = threadIdx.x;
    const int lane = tid & 63;
    const int wave = tid >> 6;
    const int wr   = wave >> 2, wc = wave & 3;
    const int rl   = lane & 15, lq = lane >> 4;

    const int m0 = by * 128, n0 = bx * 128;

    f32x4 acc[4][2] = {};

    auto compute = [&](const u16* Ac, const u16* Bc) {
#pragma unroll
        for (int kk = 0; kk < 2; kk++) {
            bf16x8 af[4], bfr[2];
#pragma unroll
            for (int mi = 0; mi < 4; mi++)
                af[mi] = *(const bf16x8*)(Ac +
                    (size_t)((kk * 4 + lq) * 128 + wr * 64 + mi * 16 + rl) * 8);
#pragma unroll
            for (int ni = 0; ni < 2; ni++)
                bfr[ni] = *(const bf16x8*)(Bc +
                    (size_t)((kk * 4 + lq) * 128 + wc * 32 + ni * 16 + rl) * 8);
#pragma unroll
            for (int mi = 0; mi < 4; mi++)
#pragma unroll
                for (int ni = 0; ni < 2; ni++)
                    acc[mi][ni] = MFMA16(af[mi], bfr[ni], acc[mi][ni]);
        }
    };

    stage_op(Ao, BTo, m0, n0, 0,  tid, As[0], Bs[0]);
    stage_op(Ao, BTo, m0, n0, 64, tid, As[1], Bs[1]);

    int cur = 0;
    for (int i = 0; i < 15; i++) {               // K' = 1024 -> 16 K-tiles
        asm volatile("s_waitcnt vmcnt(4)" ::: "memory");
        __builtin_amdgcn_s_barrier();
        compute(As[cur], Bs[cur]);
        asm volatile("s_waitcnt lgkmcnt(0)" ::: "memory");
        __builtin_amdgcn_s_barrier();
        if (i + 2 < 16)
            stage_op(Ao, BTo, m0, n0, (i + 2) * 64, tid, As[cur], Bs[cur]);
        cur ^= 1;
    }
    asm volatile("s_waitcnt vmcnt(0)" ::: "memory");
    __builtin_amdgcn_s_barrier();
    compute(As[cur], Bs[cur]);

#pragma unroll
    for (int mi = 0; mi < 4; mi++)
#pragma unroll
        for (int ni = 0; ni < 2; ni++) {
            int n = n0 + wc * 32 + ni * 16 + rl;
            float bb = bo[n];
#pragma unroll
            for (int r = 0; r < 4; r++) {
                int m = m0 + wr * 64 + mi * 16 + lq * 4 + r;
                O[(size_t)m * EE + n] = acc[mi][ni][r] + bb;
            }
        }
}

// ---------------------------------------------------------------------------
// MFMA flash attention (fixed-max softmax, QBLK=128, 8 waves) — R19 structure
// (58 KB LDS, single-buffered KVBLK=64) + R21 XCD-affine block mapping:
// bh = (wg&7) + 8*((wg>>3)&7)  (bh%8 == XCD), q0 = (wg>>6)*128.
// Each XCD's 8 bh => 2 MB K/V resident in its private L2.
// ---------------------------------------------------------------------------
__device__ __forceinline__ bf16x8 ld_frag(const u16* base, int row, int col)
{
    int off = (row * 128 + col * 2) ^ ((row & 7) << 4);
    return *(const bf16x8*)((const char*)base + off);
}

__global__ __launch_bounds__(512) void attn_mfma(
    const u16* __restrict__ qb, const u16* __restrict__ kb,
    const u16* __restrict__ vtb,
    const float* __restrict__ relk, const float* __restrict__ relv,
    __bf16* __restrict__ Ao)
{
    __shared__ __attribute__((aligned(16))) u16 pool[16384];   // 32 KB: q(16) + p(16)
    __shared__ __attribute__((aligned(16))) u16 k_lds[64 * 64];
    __shared__ __attribute__((aligned(16))) u16 v_lds[64 * 64];
    __shared__ float R_lds[128 * 9];
    __shared__ float rk_lds[9 * 64];
    __shared__ float rv_lds[9 * 64];

    u16* q_lds = pool;            // 8192 u16

    const int tid  = threadIdx.x;
    const int lane = tid & 63;
    const int wave = tid >> 6;                   // 0..7
    const int rl   = lane & 15, lq = lane >> 4;
    const int wg   = blockIdx.x;                 // 0..511
    const int bh   = (wg & 7) + 8 * ((wg >> 3) & 7);   // bh%8 == XCD
    const int q0   = (wg >> 6) * 128;            // 0..7 q-blocks

    // ---- stage Q block (128x64 bf16) with inverse-swizzled source ----
#pragma unroll
    for (int rr = 0; rr < 2; rr++) {
        int f = rr * 512 + tid;
        int row = f >> 3, c8 = f & 7;
        const u16* src = qb + ((size_t)bh * LQ + q0 + row) * HD + ((c8 ^ (row & 7)) * 8);
        __builtin_amdgcn_global_load_lds(src, q_lds + (size_t)(f & ~63) * 8, 16, 0, 0);
    }
    for (int u = tid; u < 144; u += 512)
        *(float4*)&rk_lds[u * 4] = *(const float4*)&relk[u * 4];
    for (int u = tid; u < 144; u += 512)
        *(float4*)&rv_lds[u * 4] = *(const float4*)&relv[u * 4];
    __syncthreads();

    // ---- R[t][i] = q[t] . relk[i]  (128 x 9) ----
    for (int j = tid; j < 1152; j += 512) {
        int tl = j / 9, i = j - tl * 9;
        float acc = 0.f;
        for (int d = 0; d < 64; d++) {
            int off = (tl * 128 + d * 2) ^ ((tl & 7) << 4);
            float qv = (float)*(const __bf16*)((const char*)q_lds + off);
            acc += qv * rk_lds[i * 64 + d];
        }
        R_lds[tl * 9 + i] = acc;
    }

    bf16x8 qa[2];
    qa[0] = ld_frag(q_lds, wave * 16 + rl, lq * 8);
    qa[1] = ld_frag(q_lds, wave * 16 + rl, 32 + lq * 8);

    __syncthreads();

    f32x4 of[4] = {};
    float l_r[4] = {0.f, 0.f, 0.f, 0.f};

    const u16* pw = pool + 8192 + wave * 1024;
    u16* pww      = pool + 8192 + wave * 1024;

    for (int s0 = 0; s0 < LQ; s0 += 64) {
        {
            int row = tid >> 3, c8 = tid & 7;
            const u16* srck = kb + ((size_t)bh * LQ + s0 + row) * HD + ((c8 ^ (row & 7)) * 8);
            __builtin_amdgcn_global_load_lds(srck, k_lds + (size_t)(tid & ~63) * 8, 16, 0, 0);
            const u16* srcv = vtb + ((size_t)bh * HD + row) * LQ + s0 + ((c8 ^ (row & 7)) * 8);
            __builtin_amdgcn_global_load_lds(srcv, v_lds + (size_t)(tid & ~63) * 8, 16, 0, 0);
        }
        __syncthreads();

        // ---- S = Q @ K^T ----
        f32x4 sf[4] = {};
#pragma unroll
        for (int sub = 0; sub < 4; sub++) {
#pragma unroll
            for (int kk = 0; kk < 2; kk++) {
                bf16x8 kf = ld_frag(k_lds, sub * 16 + rl, kk * 32 + lq * 8);
                sf[sub] = MFMA16(qa[kk], kf, sf[sub]);
            }
        }

        int drel = s0 - q0;
        bool diag = (drel >= -64) && (drel <= 128);
        if (diag) {
#pragma unroll
            for (int sub = 0; sub < 4; sub++) {
#pragma unroll
                for (int r = 0; r < 4; r++) {
                    int tl = wave * 16 + lq * 4 + r;
                    int s  = s0 + sub * 16 + rl;
                    int i  = s - (q0 + tl) + 4;
                    if ((unsigned)i <= 8u) sf[sub][r] += R_lds[tl * 9 + i];
                }
            }
        }

        // ---- P = exp(S), accumulate l, store bf16 ----
#pragma unroll
        for (int sub = 0; sub < 4; sub++) {
#pragma unroll
            for (int r = 0; r < 4; r++) {
                float p = __expf(sf[sub][r]);
                l_r[r] += p;
                int q = lq * 4 + r;
                int off = (q * 128 + (sub * 16 + rl) * 2) ^ ((q & 7) << 4);
                *(__bf16*)((char*)pww + off) = (__bf16)p;
            }
        }

        // ---- O += P @ V ----
#pragma unroll
        for (int kk = 0; kk < 2; kk++) {
            bf16x8 pa = ld_frag(pw, rl, kk * 32 + lq * 8);
#pragma unroll
            for (int dsub = 0; dsub < 4; dsub++) {
                bf16x8 vf = ld_frag(v_lds, dsub * 16 + rl, kk * 32 + lq * 8);
                of[dsub] = MFMA16(pa, vf, of[dsub]);
            }
        }

        // ---- windowed rel-v term ----
        if (diag) {
#pragma unroll
            for (int r = 0; r < 4; r++) {
                int q  = lq * 4 + r;
                int tl = wave * 16 + q;
#pragma unroll
                for (int i = 0; i < 9; i++) {
                    int s  = q0 + tl + i - 4;
                    int sl = s - s0;
                    if ((unsigned)sl < 64u) {
                        int off = (q * 128 + sl * 2) ^ ((q & 7) << 4);
                        float p = (float)*(const __bf16*)((const char*)pww + off);
#pragma unroll
                        for (int dsub = 0; dsub < 4; dsub++)
                            of[dsub][r] += p * rv_lds[i * 64 + dsub * 16 + rl];
                    }
                }
            }
        }
        __syncthreads();
    }

    // ---- final normalize ----
#pragma unroll
    for (int r = 0; r < 4; r++) {
        float s = l_r[r];
#pragma unroll
        for (int msk = 8; msk >= 1; msk >>= 1) s += __shfl_xor(s, msk, 64);
        l_r[r] = 1.0f / s;
    }

    // ---- stage hi tile (128 x 64) into pool, then coalesced write ----
#pragma unroll
    for (int dsub = 0; dsub < 4; dsub++) {
#pragma unroll
        for (int r = 0; r < 4; r++) {
            int row = wave * 16 + lq * 4 + r;       // 0..127
            float v = of[dsub][r] * l_r[r];
            int col = dsub * 16 + rl;               // 0..63
            int c = col >> 3, j = col & 7;
            pool[(row * 8 + (c ^ (row & 7))) * 8 + j] = bf16_bits((__bf16)v);
        }
    }
    __syncthreads();
    const int b = bh >> 4, h = bh & 15;
#pragma unroll
    for (int it = 0; it < 2; it++) {
        int id = it * 512 + tid;                    // 1024 16B-chunks
        int row = id >> 3, c = id & 7;
        bf16x8 vv = *(const bf16x8*)&pool[(row * 8 + (c ^ (row & 7))) * 8];
        __bf16* dst = Ao + ((size_t)(b * LQ) + q0 + row) * 1024 + h * 64 + c * 8;
        *(bf16x8*)dst = vv;
    }
}

// ---------------------------------------------------------------------------
extern "C" void kernel_launch(void* const* d_in, const int* in_sizes, int n_in,
                              void* d_out, int out_size, void* d_ws, size_t ws_size,
                              hipStream_t stream)
{
    const float* hidden = (const float*)d_in[0];
    const float* Wq = (const float*)d_in[1];
    const float* bq = (const float*)d_in[2];
    const float* Wk = (const float*)d_in[3];
    const float* bk = (const float*)d_in[4];
    const float* Wv = (const float*)d_in[5];
    const float* bv = (const float*)d_in[6];
    const float* Wo = (const float*)d_in[7];
    const float* bo = (const float*)d_in[8];
    const float* relk = (const float*)d_in[9];
    const float* relv = (const float*)d_in[10];

    char* w = (char*)d_ws;
    // Workspace: Ah/Ao 8 MB at 0 (hi only, stride 1024); BTq 8M (2MB),
    // BTk 10M, BTv 12M (contiguous 3072 rows), BTo 14M; qbw 16M (8MB),
    // kbw 24M (8MB), vtbw 32M (8MB). 40 MB total.
    __bf16* Ah   = (__bf16*)(w);
    __bf16* Ao   = (__bf16*)(w);
    __bf16* BTq  = (__bf16*)(w + (8u << 20));
    __bf16* BTk  = (__bf16*)(w + (10u << 20));
    __bf16* BTv  = (__bf16*)(w + (12u << 20));
    __bf16* BTo  = (__bf16*)(w + (14u << 20));
    __bf16* qbw  = (__bf16*)(w + (16u << 20));
    __bf16* kbw  = (__bf16*)(w + (24u << 20));
    __bf16* vtbw = (__bf16*)(w + (32u << 20));
    float*  out  = (float*)d_out;

    conv_all<<<2048, 256, 0, stream>>>(hidden, Wq, Wk, Wv, Wo, Ah,
                                       BTq, BTk, BTv, BTo);
    qkv_mfma<<<192, 512, 0, stream>>>((const u16*)Ah, (const u16*)BTq,
                                      bq, bk, bv, qbw, kbw, vtbw);
    attn_mfma<<<512, 512, 0, stream>>>((const u16*)qbw, (const u16*)kbw,
        (const u16*)vtbw, relk, relv, Ao);
    oproj_mfma<<<256, 512, 0, stream>>>((const u16*)Ao, (const u16*)BTo, bo, out);
}